// Round 7
// baseline (311.359 us; speedup 1.0000x reference)
//
#include <hip/hip_runtime.h>
#include <cstdint>
#include <cstddef>

// ---------------------------------------------------------------------------
// ReLA block: y = LN2( (causal_relu( (LN1(x)Wq*s) (LN1(x)Wk)^T ) (LN1(x)Wv)) Wout )
// x: [2,2048,1024] fp32. HEADS=16, DIM_HEAD=64, DIM=1024. Output fp32.
// bf16 MFMA (16x16x32) everywhere, fp32 accumulate.
// R6 attention: LDS-read-pipe was ~70% busy (36 b128 reads/iter/wave).
//   (1) phase-1 bk/bv fragments read ONCE, shared by both sub-tile units;
//   (2) phase-2 second tile loads fragments DIRECT from global (L2-local),
//       shrinking K/V staging to single-tile buffers: LDS 73KB -> 41KB
//       -> 3 blocks/CU. Uniform 17 iterations, h-major grid retained.
// ---------------------------------------------------------------------------

typedef __bf16 bf16_t;
typedef __bf16 bf16x8 __attribute__((ext_vector_type(8)));
typedef __bf16 bf16x4 __attribute__((ext_vector_type(4)));
typedef float  f32x4  __attribute__((ext_vector_type(4)));

#define DEV_INLINE __device__ __forceinline__

// async global->LDS, 16B per lane. LDS dest is wave-uniform base + lane*16.
DEV_INLINE void async_copy16(void* lds, const void* g) {
  __builtin_amdgcn_global_load_lds(
      (__attribute__((address_space(1))) void*)(g),
      (__attribute__((address_space(3))) void*)(lds), 16, 0, 0);
}

// ---------------------------------------------------------------------------
// LN1: x fp32 [4096,1024] -> xn bf16 [4096,1024]
// ---------------------------------------------------------------------------
__global__ __launch_bounds__(256) void ln1_kernel(
    const float* __restrict__ x, const float* __restrict__ g,
    const float* __restrict__ bta, bf16_t* __restrict__ xn) {
  const int row = blockIdx.x;
  const int t = threadIdx.x, w = t >> 6, l = t & 63;
  const float* xr = x + (size_t)row * 1024;
  float4 v = *(const float4*)(xr + t * 4);
  float s  = v.x + v.y + v.z + v.w;
  float s2 = v.x * v.x + v.y * v.y + v.z * v.z + v.w * v.w;
  #pragma unroll
  for (int off = 32; off >= 1; off >>= 1) {
    s  += __shfl_down(s, off);
    s2 += __shfl_down(s2, off);
  }
  __shared__ float red[8];
  if (l == 0) { red[w] = s; red[4 + w] = s2; }
  __syncthreads();
  s  = red[0] + red[1] + red[2] + red[3];
  s2 = red[4] + red[5] + red[6] + red[7];
  float mu  = s * (1.0f / 1024.0f);
  float var = s2 * (1.0f / 1024.0f) - mu * mu;
  float rs  = rsqrtf(var + 1e-5f);
  float4 gv = *(const float4*)(g + t * 4);
  float4 bv = *(const float4*)(bta + t * 4);
  bf16x4 o;
  o[0] = (bf16_t)((v.x - mu) * rs * gv.x + bv.x);
  o[1] = (bf16_t)((v.y - mu) * rs * gv.y + bv.y);
  o[2] = (bf16_t)((v.z - mu) * rs * gv.z + bv.z);
  o[3] = (bf16_t)((v.w - mu) * rs * gv.w + bv.w);
  *(bf16x4*)(xn + (size_t)row * 1024 + t * 4) = o;
}

// ---------------------------------------------------------------------------
// LN2 (fused split-K add): z = z0 + z1, then layernorm -> out fp32
// ---------------------------------------------------------------------------
__global__ __launch_bounds__(256) void ln2_kernel(
    const float* __restrict__ z0, const float* __restrict__ z1,
    const float* __restrict__ g, const float* __restrict__ bta,
    float* __restrict__ out) {
  const int row = blockIdx.x;
  const int t = threadIdx.x, w = t >> 6, l = t & 63;
  float4 v  = *(const float4*)(z0 + (size_t)row * 1024 + t * 4);
  float4 v1 = *(const float4*)(z1 + (size_t)row * 1024 + t * 4);
  v.x += v1.x; v.y += v1.y; v.z += v1.z; v.w += v1.w;
  float s  = v.x + v.y + v.z + v.w;
  float s2 = v.x * v.x + v.y * v.y + v.z * v.z + v.w * v.w;
  #pragma unroll
  for (int off = 32; off >= 1; off >>= 1) {
    s  += __shfl_down(s, off);
    s2 += __shfl_down(s2, off);
  }
  __shared__ float red[8];
  if (l == 0) { red[w] = s; red[4 + w] = s2; }
  __syncthreads();
  s  = red[0] + red[1] + red[2] + red[3];
  s2 = red[4] + red[5] + red[6] + red[7];
  float mu  = s * (1.0f / 1024.0f);
  float var = s2 * (1.0f / 1024.0f) - mu * mu;
  float rs  = rsqrtf(var + 1e-5f);
  float4 gv = *(const float4*)(g + t * 4);
  float4 bv = *(const float4*)(bta + t * 4);
  float4 o;
  o.x = (v.x - mu) * rs * gv.x + bv.x;
  o.y = (v.y - mu) * rs * gv.y + bv.y;
  o.z = (v.z - mu) * rs * gv.z + bv.z;
  o.w = (v.w - mu) * rs * gv.w + bv.w;
  *(float4*)(out + (size_t)row * 1024 + t * 4) = o;
}

// ---------------------------------------------------------------------------
// Weight transpose+convert: w fp32 [1024][N] -> wT bf16 [N][1024]
// ---------------------------------------------------------------------------
__global__ __launch_bounds__(256) void wtrans_kernel(
    const float* __restrict__ wsrc, bf16_t* __restrict__ wdstT, int N) {
  __shared__ __align__(16) float tl[64][68];
  const int n0 = blockIdx.x * 64, k0 = blockIdx.y * 64;
  const int t = threadIdx.x;
  #pragma unroll
  for (int c = 0; c < 4; ++c) {
    int idx = c * 256 + t;
    int r = idx >> 4, c4 = (idx & 15) * 4;
    *(float4*)&tl[r][c4] = *(const float4*)(wsrc + (size_t)(k0 + r) * N + n0 + c4);
  }
  __syncthreads();
  #pragma unroll
  for (int c = 0; c < 2; ++c) {
    int idx = c * 256 + t;
    int nl = idx >> 3, kc = (idx & 7) * 8;
    bf16x8 o;
    #pragma unroll
    for (int ii = 0; ii < 8; ++ii) o[ii] = (bf16_t)tl[kc + ii][nl];
    *(bf16x8*)(wdstT + (size_t)(n0 + nl) * 1024 + k0 + kc) = o;
  }
}

// ---------------------------------------------------------------------------
// V transpose: v bf16 [b,h,n,64] -> vT bf16 [b,h,64,n]   (n=2048)
// ---------------------------------------------------------------------------
__global__ __launch_bounds__(256) void vtrans_kernel(
    const bf16_t* __restrict__ v, bf16_t* __restrict__ vT) {
  __shared__ __align__(16) bf16_t tl[64][72];
  const int n0 = blockIdx.x * 64;
  const size_t bh = blockIdx.y;
  const int t = threadIdx.x;
  #pragma unroll
  for (int c = 0; c < 2; ++c) {
    int idx = c * 256 + t;
    int r = idx >> 3, c8 = (idx & 7) * 8;
    *(bf16x8*)&tl[r][c8] = *(const bf16x8*)(v + (bh * 2048 + n0 + r) * 64 + c8);
  }
  __syncthreads();
  #pragma unroll
  for (int c = 0; c < 2; ++c) {
    int idx = c * 256 + t;
    int d = idx >> 3, nc = (idx & 7) * 8;
    bf16x8 o;
    #pragma unroll
    for (int ii = 0; ii < 8; ++ii) o[ii] = tl[nc + ii][d];
    *(bf16x8*)(vT + (bh * 64 + d) * 2048 + n0 + nc) = o;
  }
}

// ---------------------------------------------------------------------------
// GEMM: C[M,N] = A[M,1024] @ Bt[N,1024]^T, bf16 in, fp32 acc.
// KSPLIT=2: blockIdx.z picks K-half; kz=0 -> C0, kz=1 -> C1 (fp32 partials).
// EPI=1: qkv split epilogue -> q(*0.125)/k/v bf16 [b,h,2048,64].
// ---------------------------------------------------------------------------
template <int EPI, int KSPLIT>
__global__ __launch_bounds__(256, 3) void gemm128_kernel(
    const bf16_t* __restrict__ A, const bf16_t* __restrict__ Bt,
    void* __restrict__ C0, void* __restrict__ C1, void* __restrict__ C2) {
  __shared__ __align__(16) bf16_t As[128 * 32];
  __shared__ __align__(16) bf16_t Bs[128 * 32];
  const int t = threadIdx.x;
  const int w = t >> 6, l = t & 63, l15 = l & 15, quad = l >> 4;
  const int wy = w >> 1, wx = w & 1;
  const int m0 = blockIdx.y * 128, n0 = blockIdx.x * 128;
  const int kz = (KSPLIT > 1) ? blockIdx.z : 0;
  const int kt0 = kz * (32 / KSPLIT), kt1 = kt0 + (32 / KSPLIT);

  int arow[2], acol[2];
  #pragma unroll
  for (int c = 0; c < 2; ++c) {
    int e = (w * 2 + c) * 512 + l * 8;
    arow[c] = e >> 5;
    acol[c] = e & 31;
  }

  f32x4 acc[4][4];
  #pragma unroll
  for (int i = 0; i < 4; ++i)
    #pragma unroll
    for (int j = 0; j < 4; ++j) acc[i][j] = (f32x4)0.0f;

  for (int kt = kt0; kt < kt1; ++kt) {
    __syncthreads();
    #pragma unroll
    for (int c = 0; c < 2; ++c) {
      async_copy16(&As[(w * 2 + c) * 512],
                   A + (size_t)(m0 + arow[c]) * 1024 + kt * 32 + acol[c]);
      async_copy16(&Bs[(w * 2 + c) * 512],
                   Bt + (size_t)(n0 + arow[c]) * 1024 + kt * 32 + acol[c]);
    }
    __syncthreads();
    bf16x8 af[4], bfr[4];
    #pragma unroll
    for (int i = 0; i < 4; ++i)
      af[i] = *(const bf16x8*)&As[(wy * 64 + i * 16 + l15) * 32 + quad * 8];
    #pragma unroll
    for (int j = 0; j < 4; ++j)
      bfr[j] = *(const bf16x8*)&Bs[(wx * 64 + j * 16 + l15) * 32 + quad * 8];
    #pragma unroll
    for (int i = 0; i < 4; ++i)
      #pragma unroll
      for (int j = 0; j < 4; ++j)
        acc[i][j] = __builtin_amdgcn_mfma_f32_16x16x32_bf16(af[i], bfr[j], acc[i][j], 0, 0, 0);
  }

  if (EPI == 0) {
    float* C = (float*)(kz == 0 ? C0 : C1);   // explicit partial destinations
    #pragma unroll
    for (int i = 0; i < 4; ++i)
      #pragma unroll
      for (int j = 0; j < 4; ++j)
        #pragma unroll
        for (int r = 0; r < 4; ++r) {
          int m = m0 + wy * 64 + i * 16 + quad * 4 + r;
          int n = n0 + wx * 64 + j * 16 + l15;
          C[(size_t)m * 1024 + n] = acc[i][j][r];
        }
  } else {
    int nb = n0 + wx * 64;
    int which = nb >> 10;
    int head = (nb & 1023) >> 6;
    bf16_t* dst = which == 0 ? (bf16_t*)C0 : which == 1 ? (bf16_t*)C1 : (bf16_t*)C2;
    float sc = which == 0 ? 0.125f : 1.0f;
    #pragma unroll
    for (int i = 0; i < 4; ++i)
      #pragma unroll
      for (int j = 0; j < 4; ++j)
        #pragma unroll
        for (int r = 0; r < 4; ++r) {
          int m = m0 + wy * 64 + i * 16 + quad * 4 + r;
          int bq = m >> 11, pos = m & 2047;
          int d = j * 16 + l15;
          dst[(((size_t)(bq * 16 + head)) * 2048 + pos) * 64 + d] =
              (bf16_t)(acc[i][j][r] * sc);
        }
  }
}

// ---------------------------------------------------------------------------
// Causal ReLU attention, R6.
// Block (h=bx, p=by, b=bz): sub-tiles tA=p, tB=31-p (33 key-units), uniform
// 17 iterations. Phase 1 (it<=p): one staged tile, fragments read ONCE from
// LDS and shared by both sub-tile units. Phase 2: first tile staged (LDS),
// second tile fragments DIRECT from global (L2-local via h-major grid).
// K/V single-tile double buffers (LDS 41KB -> 3 blocks/CU). Ss wave-private.
// ---------------------------------------------------------------------------
__global__ __launch_bounds__(256, 3) void attn_kernel(
    const bf16_t* __restrict__ q, const bf16_t* __restrict__ k,
    const bf16_t* __restrict__ vT, bf16_t* __restrict__ out) {
  __shared__ __align__(16) bf16_t Ks[2][64 * 64];   // 2 x 8 KB
  __shared__ __align__(16) bf16_t Vts[2][64 * 64];  // 2 x 8 KB
  __shared__ __align__(16) bf16_t Ss[64 * 72];      // 9 KB, wave-private rows

  const int h = blockIdx.x, p = blockIdx.y, b = blockIdx.z;
  const int t = threadIdx.x;
  const int w = t >> 6, l = t & 63, l15 = l & 15, quad = l >> 4;
  const size_t bh = (size_t)(b * 16 + h);
  const int tB = 31 - p;

  const int r_l = l >> 3;            // row within 8-row chunk
  const int u_g = (l & 7) ^ r_l;     // swizzled source 8-elem unit
  const int rswz = l15 & 7;          // read-side swizzle key

  // stage one 64-key tile kt2 into buffer buf (swizzled layout)
  auto stage_tile = [&](int buf, int kt2) {
    #pragma unroll
    for (int c = 0; c < 2; ++c) {
      int idx = w * 2 + c;                    // 0..7
      int row = idx * 8 + r_l;                // 0..63
      async_copy16(&Ks[buf][idx * 512],
                   k + (bh * 2048 + kt2 * 64 + row) * 64 + u_g * 8);
      async_copy16(&Vts[buf][idx * 512],
                   vT + (bh * 64 + row) * 2048 + kt2 * 64 + u_g * 8);
    }
  };
  auto stage_it = [&](int it, int buf) {
    int kt2 = (it <= p) ? it : (p + 1 + 2 * (it - p - 1));
    stage_tile(buf, kt2);
  };

  // read a staged tile's fragments from LDS (once)
  auto load_lds = [&](const bf16_t* Kb, const bf16_t* Vb,
                      bf16x8 (&bk)[2][4], bf16x8 (&bv)[2][4]) {
    #pragma unroll
    for (int kk = 0; kk < 2; ++kk)
      #pragma unroll
      for (int tj = 0; tj < 4; ++tj) {
        int u = ((kk * 4 + quad) ^ rswz) * 8;
        bk[kk][tj] = *(const bf16x8*)&Kb[(tj * 16 + l15) * 64 + u];
        bv[kk][tj] = *(const bf16x8*)&Vb[(tj * 16 + l15) * 64 + u];
      }
  };
  // read a tile's fragments direct from global (L2-resident)
  auto load_global = [&](int kt2, bf16x8 (&bk)[2][4], bf16x8 (&bv)[2][4]) {
    #pragma unroll
    for (int kk = 0; kk < 2; ++kk)
      #pragma unroll
      for (int tj = 0; tj < 4; ++tj) {
        bk[kk][tj] = *(const bf16x8*)(k  + (bh * 2048 + kt2 * 64 + tj * 16 + l15) * 64
                                         + kk * 32 + quad * 8);
        bv[kk][tj] = *(const bf16x8*)(vT + (bh * 64 + tj * 16 + l15) * 2048
                                         + kt2 * 64 + kk * 32 + quad * 8);
      }
  };

  bf16x8 qa[2][2];
  {
    int rA = p * 64 + w * 16, rB = tB * 64 + w * 16;
    #pragma unroll
    for (int kk = 0; kk < 2; ++kk) {
      qa[0][kk] = *(const bf16x8*)(q + (bh * 2048 + rA + l15) * 64 + kk * 32 + quad * 8);
      qa[1][kk] = *(const bf16x8*)(q + (bh * 2048 + rB + l15) * 64 + kk * 32 + quad * 8);
    }
  }

  f32x4 acc0[4], acc1[4];
  #pragma unroll
  for (int tj = 0; tj < 4; ++tj) { acc0[tj] = (f32x4)0.0f; acc1[tj] = (f32x4)0.0f; }

  // one 64-key unit on given fragments: S = Qf.K^T, relu+mask, O += S.V
  auto unit = [&](f32x4 (&accr)[4], bf16x8 (&qf)[2],
                  bf16x8 (&bk)[2][4], bf16x8 (&bv)[2][4], bool dg) {
    f32x4 sacc[4];
    #pragma unroll
    for (int tj = 0; tj < 4; ++tj) sacc[tj] = (f32x4)0.0f;
    #pragma unroll
    for (int kk = 0; kk < 2; ++kk)
      #pragma unroll
      for (int tj = 0; tj < 4; ++tj)
        sacc[tj] = __builtin_amdgcn_mfma_f32_16x16x32_bf16(qf[kk], bk[kk][tj], sacc[tj], 0, 0, 0);
    #pragma unroll
    for (int tj = 0; tj < 4; ++tj)
      #pragma unroll
      for (int r = 0; r < 4; ++r) {
        float v = fmaxf(sacc[tj][r], 0.0f);
        if (dg && (tj * 16 + l15 > w * 16 + quad * 4 + r)) v = 0.0f;
        Ss[(w * 16 + quad * 4 + r) * 72 + tj * 16 + l15] = (bf16_t)v;
      }
    #pragma unroll
    for (int kk = 0; kk < 2; ++kk) {
      bf16x8 as_ = *(const bf16x8*)&Ss[(w * 16 + l15) * 72 + kk * 32 + quad * 8];
      #pragma unroll
      for (int tj = 0; tj < 4; ++tj)
        accr[tj] = __builtin_amdgcn_mfma_f32_16x16x32_bf16(as_, bv[kk][tj], accr[tj], 0, 0, 0);
    }
  };

  stage_it(0, 0);
  for (int it = 0; it < 17; ++it) {
    __syncthreads();  // drains this buffer's async loads; fences reuse
    if (it + 1 < 17) stage_it(it + 1, (it + 1) & 1);
    const int buf = it & 1;
    if (it <= p) {
      // one staged tile, fragments shared by both sub-tile units
      bf16x8 bk[2][4], bv[2][4];
      load_lds(&Ks[buf][0], &Vts[buf][0], bk, bv);
      unit(acc0, qa[0], bk, bv, it == p);
      unit(acc1, qa[1], bk, bv, false);
    } else {
      int base = p + 1 + 2 * (it - p - 1);
      bool second = (base + 1 <= tB);     // block-uniform
      bf16x8 bk2[2][4], bv2[2][4];
      if (second) load_global(base + 1, bk2, bv2);   // in flight during staged unit
      bf16x8 bk[2][4], bv[2][4];
      load_lds(&Ks[buf][0], &Vts[buf][0], bk, bv);
      unit(acc1, qa[1], bk, bv, base == tB);
      if (second) unit(acc1, qa[1], bk2, bv2, base + 1 == tB);
    }
  }

  // epilogue: out[b][pos][h*64+d]
  #pragma unroll
  for (int tj = 0; tj < 4; ++tj)
    #pragma unroll
    for (int r = 0; r < 4; ++r) {
      int col = h * 64 + tj * 16 + l15;
      int posA = p * 64 + w * 16 + quad * 4 + r;
      int posB = tB * 64 + w * 16 + quad * 4 + r;
      out[((size_t)b * 2048 + posA) * 1024 + col] = (bf16_t)acc0[tj][r];
      out[((size_t)b * 2048 + posB) * 1024 + col] = (bf16_t)acc1[tj][r];
    }
}

// ---------------------------------------------------------------------------
// launch
// ---------------------------------------------------------------------------
extern "C" void kernel_launch(void* const* d_in, const int* in_sizes, int n_in,
                              void* d_out, int out_size, void* d_ws, size_t ws_size,
                              hipStream_t stream) {
  (void)in_sizes; (void)n_in; (void)out_size; (void)ws_size;
  const float* x     = (const float*)d_in[0];
  const float* ln1_g = (const float*)d_in[1];
  const float* ln1_b = (const float*)d_in[2];
  const float* w_qkv = (const float*)d_in[3];
  const float* w_out = (const float*)d_in[4];
  const float* ln2_g = (const float*)d_in[5];
  const float* ln2_b = (const float*)d_in[6];
  float* out = (float*)d_out;

  char* ws = (char*)d_ws;
  bf16_t* xn     = (bf16_t*)(ws + 0);          //  8,388,608  [4096,1024]
  bf16_t* wqkvT  = (bf16_t*)(ws + 8388608);    //  6,291,456  [3072,1024]
  bf16_t* woutT  = (bf16_t*)(ws + 14680064);   //  2,097,152  [1024,1024]
  bf16_t* qb     = (bf16_t*)(ws + 16777216);   //  8,388,608  [2,16,2048,64]
  bf16_t* kb     = (bf16_t*)(ws + 25165824);   //  8,388,608
  bf16_t* vb     = (bf16_t*)(ws + 33554432);   //  8,388,608
  bf16_t* vTb    = (bf16_t*)(ws + 41943040);   //  8,388,608  [2,16,64,2048]
  bf16_t* ao     = (bf16_t*)(ws + 50331648);   //  8,388,608  [4096,1024]
  float*  z0     = (float*)(ws + 58720256);    // 16,777,216  [4096,1024]
  float*  z1     = (float*)(ws + 16777216);    // 16 MB, reuses qb+kb (dead after attn)

  ln1_kernel<<<4096, 256, 0, stream>>>(x, ln1_g, ln1_b, xn);
  wtrans_kernel<<<dim3(48, 16), 256, 0, stream>>>(w_qkv, wqkvT, 3072);
  wtrans_kernel<<<dim3(16, 16), 256, 0, stream>>>(w_out, woutT, 1024);
  gemm128_kernel<1, 1><<<dim3(24, 32), 256, 0, stream>>>(xn, wqkvT, qb, kb, vb);
  vtrans_kernel<<<dim3(32, 32), 256, 0, stream>>>(vb, vTb);
  attn_kernel<<<dim3(16, 16, 2), 256, 0, stream>>>(qb, kb, vTb, ao);
  gemm128_kernel<0, 2><<<dim3(8, 32, 2), 256, 0, stream>>>(ao, woutT, z0, z1, nullptr);
  ln2_kernel<<<4096, 256, 0, stream>>>(z0, z1, ln2_g, ln2_b, out);
}

// Round 8
// 186.772 us; speedup vs baseline: 1.6671x; 1.6671x over previous
//
#include <hip/hip_runtime.h>
#include <cstdint>
#include <cstddef>

// ---------------------------------------------------------------------------
// ReLA block: y = LN2( (causal_relu( (LN1(x)Wq*s) (LN1(x)Wk)^T ) (LN1(x)Wv)) Wout )
// x: [2,2048,1024] fp32. HEADS=16, DIM_HEAD=64, DIM=1024. Output fp32.
// bf16 MFMA (16x16x32) everywhere, fp32 accumulate.
// R7: attn = R5 (uniform 17 it, h-major, two-tile LDS staging) with shared
//     per-tile fragment loads and launch_bounds(256,2) (R6's (256,3)+dual
//     fragment sets spilled: WRITE 186MB). GEMMs: BK=64 (half the barriers)
//     with XOR-swizzled staging (2-way bank aliasing, free).
// ---------------------------------------------------------------------------

typedef __bf16 bf16_t;
typedef __bf16 bf16x8 __attribute__((ext_vector_type(8)));
typedef __bf16 bf16x4 __attribute__((ext_vector_type(4)));
typedef float  f32x4  __attribute__((ext_vector_type(4)));

#define DEV_INLINE __device__ __forceinline__

// async global->LDS, 16B per lane. LDS dest is wave-uniform base + lane*16.
DEV_INLINE void async_copy16(void* lds, const void* g) {
  __builtin_amdgcn_global_load_lds(
      (__attribute__((address_space(1))) void*)(g),
      (__attribute__((address_space(3))) void*)(lds), 16, 0, 0);
}

// ---------------------------------------------------------------------------
// LN1: x fp32 [4096,1024] -> xn bf16 [4096,1024]
// ---------------------------------------------------------------------------
__global__ __launch_bounds__(256) void ln1_kernel(
    const float* __restrict__ x, const float* __restrict__ g,
    const float* __restrict__ bta, bf16_t* __restrict__ xn) {
  const int row = blockIdx.x;
  const int t = threadIdx.x, w = t >> 6, l = t & 63;
  const float* xr = x + (size_t)row * 1024;
  float4 v = *(const float4*)(xr + t * 4);
  float s  = v.x + v.y + v.z + v.w;
  float s2 = v.x * v.x + v.y * v.y + v.z * v.z + v.w * v.w;
  #pragma unroll
  for (int off = 32; off >= 1; off >>= 1) {
    s  += __shfl_down(s, off);
    s2 += __shfl_down(s2, off);
  }
  __shared__ float red[8];
  if (l == 0) { red[w] = s; red[4 + w] = s2; }
  __syncthreads();
  s  = red[0] + red[1] + red[2] + red[3];
  s2 = red[4] + red[5] + red[6] + red[7];
  float mu  = s * (1.0f / 1024.0f);
  float var = s2 * (1.0f / 1024.0f) - mu * mu;
  float rs  = rsqrtf(var + 1e-5f);
  float4 gv = *(const float4*)(g + t * 4);
  float4 bv = *(const float4*)(bta + t * 4);
  bf16x4 o;
  o[0] = (bf16_t)((v.x - mu) * rs * gv.x + bv.x);
  o[1] = (bf16_t)((v.y - mu) * rs * gv.y + bv.y);
  o[2] = (bf16_t)((v.z - mu) * rs * gv.z + bv.z);
  o[3] = (bf16_t)((v.w - mu) * rs * gv.w + bv.w);
  *(bf16x4*)(xn + (size_t)row * 1024 + t * 4) = o;
}

// ---------------------------------------------------------------------------
// LN2 (fused split-K add): z = z0 + z1, then layernorm -> out fp32
// ---------------------------------------------------------------------------
__global__ __launch_bounds__(256) void ln2_kernel(
    const float* __restrict__ z0, const float* __restrict__ z1,
    const float* __restrict__ g, const float* __restrict__ bta,
    float* __restrict__ out) {
  const int row = blockIdx.x;
  const int t = threadIdx.x, w = t >> 6, l = t & 63;
  float4 v  = *(const float4*)(z0 + (size_t)row * 1024 + t * 4);
  float4 v1 = *(const float4*)(z1 + (size_t)row * 1024 + t * 4);
  v.x += v1.x; v.y += v1.y; v.z += v1.z; v.w += v1.w;
  float s  = v.x + v.y + v.z + v.w;
  float s2 = v.x * v.x + v.y * v.y + v.z * v.z + v.w * v.w;
  #pragma unroll
  for (int off = 32; off >= 1; off >>= 1) {
    s  += __shfl_down(s, off);
    s2 += __shfl_down(s2, off);
  }
  __shared__ float red[8];
  if (l == 0) { red[w] = s; red[4 + w] = s2; }
  __syncthreads();
  s  = red[0] + red[1] + red[2] + red[3];
  s2 = red[4] + red[5] + red[6] + red[7];
  float mu  = s * (1.0f / 1024.0f);
  float var = s2 * (1.0f / 1024.0f) - mu * mu;
  float rs  = rsqrtf(var + 1e-5f);
  float4 gv = *(const float4*)(g + t * 4);
  float4 bv = *(const float4*)(bta + t * 4);
  float4 o;
  o.x = (v.x - mu) * rs * gv.x + bv.x;
  o.y = (v.y - mu) * rs * gv.y + bv.y;
  o.z = (v.z - mu) * rs * gv.z + bv.z;
  o.w = (v.w - mu) * rs * gv.w + bv.w;
  *(float4*)(out + (size_t)row * 1024 + t * 4) = o;
}

// ---------------------------------------------------------------------------
// Weight transpose+convert: w fp32 [1024][N] -> wT bf16 [N][1024]
// ---------------------------------------------------------------------------
__global__ __launch_bounds__(256) void wtrans_kernel(
    const float* __restrict__ wsrc, bf16_t* __restrict__ wdstT, int N) {
  __shared__ __align__(16) float tl[64][68];
  const int n0 = blockIdx.x * 64, k0 = blockIdx.y * 64;
  const int t = threadIdx.x;
  #pragma unroll
  for (int c = 0; c < 4; ++c) {
    int idx = c * 256 + t;
    int r = idx >> 4, c4 = (idx & 15) * 4;
    *(float4*)&tl[r][c4] = *(const float4*)(wsrc + (size_t)(k0 + r) * N + n0 + c4);
  }
  __syncthreads();
  #pragma unroll
  for (int c = 0; c < 2; ++c) {
    int idx = c * 256 + t;
    int nl = idx >> 3, kc = (idx & 7) * 8;
    bf16x8 o;
    #pragma unroll
    for (int ii = 0; ii < 8; ++ii) o[ii] = (bf16_t)tl[kc + ii][nl];
    *(bf16x8*)(wdstT + (size_t)(n0 + nl) * 1024 + k0 + kc) = o;
  }
}

// ---------------------------------------------------------------------------
// V transpose: v bf16 [b,h,n,64] -> vT bf16 [b,h,64,n]   (n=2048)
// ---------------------------------------------------------------------------
__global__ __launch_bounds__(256) void vtrans_kernel(
    const bf16_t* __restrict__ v, bf16_t* __restrict__ vT) {
  __shared__ __align__(16) bf16_t tl[64][72];
  const int n0 = blockIdx.x * 64;
  const size_t bh = blockIdx.y;
  const int t = threadIdx.x;
  #pragma unroll
  for (int c = 0; c < 2; ++c) {
    int idx = c * 256 + t;
    int r = idx >> 3, c8 = (idx & 7) * 8;
    *(bf16x8*)&tl[r][c8] = *(const bf16x8*)(v + (bh * 2048 + n0 + r) * 64 + c8);
  }
  __syncthreads();
  #pragma unroll
  for (int c = 0; c < 2; ++c) {
    int idx = c * 256 + t;
    int d = idx >> 3, nc = (idx & 7) * 8;
    bf16x8 o;
    #pragma unroll
    for (int ii = 0; ii < 8; ++ii) o[ii] = tl[nc + ii][d];
    *(bf16x8*)(vT + (bh * 64 + d) * 2048 + n0 + nc) = o;
  }
}

// ---------------------------------------------------------------------------
// GEMM: C[M,N] = A[M,1024] @ Bt[N,1024]^T, bf16 in, fp32 acc.
// R7: BK=64 (16 K-iters), XOR-swizzled staging -> 2-way bank aliasing (free).
// KSPLIT=2: blockIdx.z picks K-half; kz=0 -> C0, kz=1 -> C1 (fp32 partials).
// EPI=1: qkv split epilogue -> q(*0.125)/k/v bf16 [b,h,2048,64].
// ---------------------------------------------------------------------------
template <int EPI, int KSPLIT>
__global__ __launch_bounds__(256, 3) void gemm128_kernel(
    const bf16_t* __restrict__ A, const bf16_t* __restrict__ Bt,
    void* __restrict__ C0, void* __restrict__ C1, void* __restrict__ C2) {
  __shared__ __align__(16) bf16_t As[128 * 64];  // 16 KB
  __shared__ __align__(16) bf16_t Bs[128 * 64];  // 16 KB
  const int t = threadIdx.x;
  const int w = t >> 6, l = t & 63, l15 = l & 15, quad = l >> 4;
  const int wy = w >> 1, wx = w & 1;
  const int m0 = blockIdx.y * 128, n0 = blockIdx.x * 128;
  const int kz = (KSPLIT > 1) ? blockIdx.z : 0;
  const int kt0 = kz * (16 / KSPLIT), kt1 = kt0 + (16 / KSPLIT);

  const int r_l = l >> 3;              // row within 8-row chunk
  const int u_src = (l & 7) ^ r_l;     // swizzled source 8-elem unit
  const int rswz = l15 & 7;            // read-side swizzle key

  f32x4 acc[4][4];
  #pragma unroll
  for (int i = 0; i < 4; ++i)
    #pragma unroll
    for (int j = 0; j < 4; ++j) acc[i][j] = (f32x4)0.0f;

  for (int kt = kt0; kt < kt1; ++kt) {
    __syncthreads();
    #pragma unroll
    for (int c = 0; c < 4; ++c) {
      int idx = w * 4 + c;             // 16 chunks of 512 elems
      int row = idx * 8 + r_l;         // 0..127
      async_copy16(&As[idx * 512], A + (size_t)(m0 + row) * 1024 + kt * 64 + u_src * 8);
      async_copy16(&Bs[idx * 512], Bt + (size_t)(n0 + row) * 1024 + kt * 64 + u_src * 8);
    }
    __syncthreads();
    #pragma unroll
    for (int kk = 0; kk < 2; ++kk) {
      bf16x8 af[4], bfr[4];
      #pragma unroll
      for (int i = 0; i < 4; ++i)
        af[i] = *(const bf16x8*)&As[(wy * 64 + i * 16 + l15) * 64 + (((kk * 4 + quad) ^ rswz) * 8)];
      #pragma unroll
      for (int j = 0; j < 4; ++j)
        bfr[j] = *(const bf16x8*)&Bs[(wx * 64 + j * 16 + l15) * 64 + (((kk * 4 + quad) ^ rswz) * 8)];
      #pragma unroll
      for (int i = 0; i < 4; ++i)
        #pragma unroll
        for (int j = 0; j < 4; ++j)
          acc[i][j] = __builtin_amdgcn_mfma_f32_16x16x32_bf16(af[i], bfr[j], acc[i][j], 0, 0, 0);
    }
  }

  if (EPI == 0) {
    float* C = (float*)(kz == 0 ? C0 : C1);   // explicit partial destinations
    #pragma unroll
    for (int i = 0; i < 4; ++i)
      #pragma unroll
      for (int j = 0; j < 4; ++j)
        #pragma unroll
        for (int r = 0; r < 4; ++r) {
          int m = m0 + wy * 64 + i * 16 + quad * 4 + r;
          int n = n0 + wx * 64 + j * 16 + l15;
          C[(size_t)m * 1024 + n] = acc[i][j][r];
        }
  } else {
    int nb = n0 + wx * 64;
    int which = nb >> 10;
    int head = (nb & 1023) >> 6;
    bf16_t* dst = which == 0 ? (bf16_t*)C0 : which == 1 ? (bf16_t*)C1 : (bf16_t*)C2;
    float sc = which == 0 ? 0.125f : 1.0f;
    #pragma unroll
    for (int i = 0; i < 4; ++i)
      #pragma unroll
      for (int j = 0; j < 4; ++j)
        #pragma unroll
        for (int r = 0; r < 4; ++r) {
          int m = m0 + wy * 64 + i * 16 + quad * 4 + r;
          int bq = m >> 11, pos = m & 2047;
          int d = j * 16 + l15;
          dst[(((size_t)(bq * 16 + head)) * 2048 + pos) * 64 + d] =
              (bf16_t)(acc[i][j][r] * sc);
        }
  }
}

// ---------------------------------------------------------------------------
// Causal ReLU attention, R7 (= R5 + shared fragment loads, no (256,3)).
// Block (h=bx, p=by, b=bz): sub-tiles tA=p, tB=31-p (33 key-units), uniform
// 17 iterations. Phase 1 (it<=p): one staged tile, fragments loaded ONCE
// from LDS, fed to both sub-tile units. Phase 2: two staged tiles, fragment
// array reused sequentially (single 64-VGPR set live). launch_bounds(256,2)
// -> 256-VGPR cap, no spill. K/V double-buffered (2x 16KB halves) via
// global_load_lds (swizzled). Ss wave-private (no barrier).
// ---------------------------------------------------------------------------
__global__ __launch_bounds__(256, 2) void attn_kernel(
    const bf16_t* __restrict__ q, const bf16_t* __restrict__ k,
    const bf16_t* __restrict__ vT, bf16_t* __restrict__ out) {
  __shared__ __align__(16) bf16_t Ks[2][128 * 64];   // 2 x 16 KB (two 64-key halves)
  __shared__ __align__(16) bf16_t Vts[2][128 * 64];  // 2 x 16 KB
  __shared__ __align__(16) bf16_t Ss[64 * 72];       // 9 KB, wave-private rows

  const int h = blockIdx.x, p = blockIdx.y, b = blockIdx.z;
  const int t = threadIdx.x;
  const int w = t >> 6, l = t & 63, l15 = l & 15, quad = l >> 4;
  const size_t bh = (size_t)(b * 16 + h);
  const int tB = 31 - p;

  const int r_l = l >> 3;            // row within 8-row chunk
  const int u_g = (l & 7) ^ r_l;     // swizzled source 8-elem unit
  const int rswz = l15 & 7;          // read-side swizzle key

  auto stage_tile = [&](int buf, int half, int kt2) {
    #pragma unroll
    for (int c = 0; c < 2; ++c) {
      int idx = w * 2 + c;                    // 0..7
      int row = idx * 8 + r_l;                // 0..63
      async_copy16(&Ks[buf][half * 4096 + idx * 512],
                   k + (bh * 2048 + kt2 * 64 + row) * 64 + u_g * 8);
      async_copy16(&Vts[buf][half * 4096 + idx * 512],
                   vT + (bh * 64 + row) * 2048 + kt2 * 64 + u_g * 8);
    }
  };
  auto stage_it = [&](int it, int buf) {
    if (it <= p) {
      stage_tile(buf, 0, it);
    } else {
      int base = p + 1 + 2 * (it - p - 1);
      stage_tile(buf, 0, base);
      int k2 = base + 1; if (k2 > 31) k2 = 31;  // clamp (compute skips > tB)
      stage_tile(buf, 1, k2);
    }
  };

  // read a staged tile's fragments from LDS (once per tile)
  auto load_lds = [&](const bf16_t* Kb, const bf16_t* Vb,
                      bf16x8 (&bk)[2][4], bf16x8 (&bv)[2][4]) {
    #pragma unroll
    for (int kk = 0; kk < 2; ++kk)
      #pragma unroll
      for (int tj = 0; tj < 4; ++tj) {
        int u = ((kk * 4 + quad) ^ rswz) * 8;
        bk[kk][tj] = *(const bf16x8*)&Kb[(tj * 16 + l15) * 64 + u];
        bv[kk][tj] = *(const bf16x8*)&Vb[(tj * 16 + l15) * 64 + u];
      }
  };

  bf16x8 qa[2][2];
  {
    int rA = p * 64 + w * 16, rB = tB * 64 + w * 16;
    #pragma unroll
    for (int kk = 0; kk < 2; ++kk) {
      qa[0][kk] = *(const bf16x8*)(q + (bh * 2048 + rA + l15) * 64 + kk * 32 + quad * 8);
      qa[1][kk] = *(const bf16x8*)(q + (bh * 2048 + rB + l15) * 64 + kk * 32 + quad * 8);
    }
  }

  f32x4 acc0[4], acc1[4];
  #pragma unroll
  for (int tj = 0; tj < 4; ++tj) { acc0[tj] = (f32x4)0.0f; acc1[tj] = (f32x4)0.0f; }

  // one 64-key unit on preloaded fragments: S = Qf.K^T, relu+mask, O += S.V
  auto unit = [&](f32x4 (&accr)[4], bf16x8 (&qf)[2],
                  bf16x8 (&bk)[2][4], bf16x8 (&bv)[2][4], bool dg) {
    f32x4 sacc[4];
    #pragma unroll
    for (int tj = 0; tj < 4; ++tj) sacc[tj] = (f32x4)0.0f;
    #pragma unroll
    for (int kk = 0; kk < 2; ++kk)
      #pragma unroll
      for (int tj = 0; tj < 4; ++tj)
        sacc[tj] = __builtin_amdgcn_mfma_f32_16x16x32_bf16(qf[kk], bk[kk][tj], sacc[tj], 0, 0, 0);
    #pragma unroll
    for (int tj = 0; tj < 4; ++tj)
      #pragma unroll
      for (int r = 0; r < 4; ++r) {
        float v = fmaxf(sacc[tj][r], 0.0f);
        if (dg && (tj * 16 + l15 > w * 16 + quad * 4 + r)) v = 0.0f;
        Ss[(w * 16 + quad * 4 + r) * 72 + tj * 16 + l15] = (bf16_t)v;
      }
    #pragma unroll
    for (int kk = 0; kk < 2; ++kk) {
      bf16x8 as_ = *(const bf16x8*)&Ss[(w * 16 + l15) * 72 + kk * 32 + quad * 8];
      #pragma unroll
      for (int tj = 0; tj < 4; ++tj)
        accr[tj] = __builtin_amdgcn_mfma_f32_16x16x32_bf16(as_, bv[kk][tj], accr[tj], 0, 0, 0);
    }
  };

  stage_it(0, 0);
  for (int it = 0; it < 17; ++it) {
    __syncthreads();  // drains this buffer's async loads; fences reuse
    if (it + 1 < 17) stage_it(it + 1, (it + 1) & 1);
    const int buf = it & 1;
    bf16x8 bk[2][4], bv[2][4];
    load_lds(&Ks[buf][0], &Vts[buf][0], bk, bv);
    if (it <= p) {
      unit(acc0, qa[0], bk, bv, it == p);      // fragments shared by both units
      unit(acc1, qa[1], bk, bv, false);
    } else {
      int base = p + 1 + 2 * (it - p - 1);
      unit(acc1, qa[1], bk, bv, base == tB);
      if (base + 1 <= tB) {                    // reuse the same array: one set live
        load_lds(&Ks[buf][4096], &Vts[buf][4096], bk, bv);
        unit(acc1, qa[1], bk, bv, base + 1 == tB);
      }
    }
  }

  // epilogue: out[b][pos][h*64+d]
  #pragma unroll
  for (int tj = 0; tj < 4; ++tj)
    #pragma unroll
    for (int r = 0; r < 4; ++r) {
      int col = h * 64 + tj * 16 + l15;
      int posA = p * 64 + w * 16 + quad * 4 + r;
      int posB = tB * 64 + w * 16 + quad * 4 + r;
      out[((size_t)b * 2048 + posA) * 1024 + col] = (bf16_t)acc0[tj][r];
      out[((size_t)b * 2048 + posB) * 1024 + col] = (bf16_t)acc1[tj][r];
    }
}

// ---------------------------------------------------------------------------
// launch
// ---------------------------------------------------------------------------
extern "C" void kernel_launch(void* const* d_in, const int* in_sizes, int n_in,
                              void* d_out, int out_size, void* d_ws, size_t ws_size,
                              hipStream_t stream) {
  (void)in_sizes; (void)n_in; (void)out_size; (void)ws_size;
  const float* x     = (const float*)d_in[0];
  const float* ln1_g = (const float*)d_in[1];
  const float* ln1_b = (const float*)d_in[2];
  const float* w_qkv = (const float*)d_in[3];
  const float* w_out = (const float*)d_in[4];
  const float* ln2_g = (const float*)d_in[5];
  const float* ln2_b = (const float*)d_in[6];
  float* out = (float*)d_out;

  char* ws = (char*)d_ws;
  bf16_t* xn     = (bf16_t*)(ws + 0);          //  8,388,608  [4096,1024]
  bf16_t* wqkvT  = (bf16_t*)(ws + 8388608);    //  6,291,456  [3072,1024]
  bf16_t* woutT  = (bf16_t*)(ws + 14680064);   //  2,097,152  [1024,1024]
  bf16_t* qb     = (bf16_t*)(ws + 16777216);   //  8,388,608  [2,16,2048,64]
  bf16_t* kb     = (bf16_t*)(ws + 25165824);   //  8,388,608
  bf16_t* vb     = (bf16_t*)(ws + 33554432);   //  8,388,608
  bf16_t* vTb    = (bf16_t*)(ws + 41943040);   //  8,388,608  [2,16,64,2048]
  bf16_t* ao     = (bf16_t*)(ws + 50331648);   //  8,388,608  [4096,1024]
  float*  z0     = (float*)(ws + 58720256);    // 16,777,216  [4096,1024]
  float*  z1     = (float*)(ws + 16777216);    // 16 MB, reuses qb+kb (dead after attn)

  ln1_kernel<<<4096, 256, 0, stream>>>(x, ln1_g, ln1_b, xn);
  wtrans_kernel<<<dim3(48, 16), 256, 0, stream>>>(w_qkv, wqkvT, 3072);
  wtrans_kernel<<<dim3(16, 16), 256, 0, stream>>>(w_out, woutT, 1024);
  gemm128_kernel<1, 1><<<dim3(24, 32), 256, 0, stream>>>(xn, wqkvT, qb, kb, vb);
  vtrans_kernel<<<dim3(32, 32), 256, 0, stream>>>(vb, vTb);
  attn_kernel<<<dim3(16, 16, 2), 256, 0, stream>>>(qb, kb, vTb, ao);
  gemm128_kernel<0, 2><<<dim3(8, 32, 2), 256, 0, stream>>>(ao, woutT, z0, z1, nullptr);
  ln2_kernel<<<4096, 256, 0, stream>>>(z0, z1, ln2_g, ln2_b, out);
}

// Round 9
// 178.557 us; speedup vs baseline: 1.7437x; 1.0460x over previous
//
#include <hip/hip_runtime.h>
#include <cstdint>
#include <cstddef>

// ---------------------------------------------------------------------------
// ReLA block: y = LN2( (causal_relu( (LN1(x)Wq*s) (LN1(x)Wk)^T ) (LN1(x)Wv)) Wout )
// x: [2,2048,1024] fp32. HEADS=16, DIM_HEAD=64, DIM=1024. Output fp32.
// bf16 MFMA (16x16x32) everywhere, fp32 accumulate.
// R8: (a) attn operand-swapped: S-matmul computes S^T (A=K,B=Q) so the
//     C-layout output is j-contiguous per lane -> Ss round-trip is 4 packed
//     ds_write_b64 per unit (was 16 scalar b16); PV swaps too (A=V^T,B=S),
//     giving O^T and a packed b64 epilogue. (b) ln1+wtrans fused into one
//     prep kernel. (c) out-proj split-K partials in bf16 (halved z traffic).
// ---------------------------------------------------------------------------

typedef __bf16 bf16_t;
typedef __bf16 bf16x8 __attribute__((ext_vector_type(8)));
typedef __bf16 bf16x4 __attribute__((ext_vector_type(4)));
typedef float  f32x4  __attribute__((ext_vector_type(4)));

#define DEV_INLINE __device__ __forceinline__

// async global->LDS, 16B per lane. LDS dest is wave-uniform base + lane*16.
DEV_INLINE void async_copy16(void* lds, const void* g) {
  __builtin_amdgcn_global_load_lds(
      (__attribute__((address_space(1))) void*)(g),
      (__attribute__((address_space(3))) void*)(lds), 16, 0, 0);
}

// ---------------------------------------------------------------------------
// prep: fused LN1 (blocks 0..4095) + wtrans(w_qkv) (4096..4863) +
//       wtrans(w_out) (4864..5119)
// ---------------------------------------------------------------------------
__global__ __launch_bounds__(256) void prep_kernel(
    const float* __restrict__ x, const float* __restrict__ g1,
    const float* __restrict__ b1, bf16_t* __restrict__ xn,
    const float* __restrict__ w_qkv, bf16_t* __restrict__ wqkvT,
    const float* __restrict__ w_out, bf16_t* __restrict__ woutT) {
  const int bid = blockIdx.x;
  const int t = threadIdx.x;
  if (bid < 4096) {
    // ---- LN1 row ----
    const int w = t >> 6, l = t & 63;
    const float* xr = x + (size_t)bid * 1024;
    float4 v = *(const float4*)(xr + t * 4);
    float s  = v.x + v.y + v.z + v.w;
    float s2 = v.x * v.x + v.y * v.y + v.z * v.z + v.w * v.w;
    #pragma unroll
    for (int off = 32; off >= 1; off >>= 1) {
      s  += __shfl_down(s, off);
      s2 += __shfl_down(s2, off);
    }
    __shared__ float red[8];
    if (l == 0) { red[w] = s; red[4 + w] = s2; }
    __syncthreads();
    s  = red[0] + red[1] + red[2] + red[3];
    s2 = red[4] + red[5] + red[6] + red[7];
    float mu  = s * (1.0f / 1024.0f);
    float var = s2 * (1.0f / 1024.0f) - mu * mu;
    float rs  = rsqrtf(var + 1e-5f);
    float4 gv = *(const float4*)(g1 + t * 4);
    float4 bv = *(const float4*)(b1 + t * 4);
    bf16x4 o;
    o[0] = (bf16_t)((v.x - mu) * rs * gv.x + bv.x);
    o[1] = (bf16_t)((v.y - mu) * rs * gv.y + bv.y);
    o[2] = (bf16_t)((v.z - mu) * rs * gv.z + bv.z);
    o[3] = (bf16_t)((v.w - mu) * rs * gv.w + bv.w);
    *(bf16x4*)(xn + (size_t)bid * 1024 + t * 4) = o;
  } else {
    // ---- weight transpose+convert: 64x64 tile ----
    const float* wsrc; bf16_t* wdst; int N, tile;
    if (bid < 4864) { wsrc = w_qkv; wdst = wqkvT; N = 3072; tile = bid - 4096; }
    else            { wsrc = w_out; wdst = woutT; N = 1024; tile = bid - 4864; }
    const int ntiles = N >> 6;
    const int n0 = (tile % ntiles) * 64, k0 = (tile / ntiles) * 64;
    __shared__ __align__(16) float tl[64][68];
    #pragma unroll
    for (int c = 0; c < 4; ++c) {
      int idx = c * 256 + t;
      int r = idx >> 4, c4 = (idx & 15) * 4;
      *(float4*)&tl[r][c4] = *(const float4*)(wsrc + (size_t)(k0 + r) * N + n0 + c4);
    }
    __syncthreads();
    #pragma unroll
    for (int c = 0; c < 2; ++c) {
      int idx = c * 256 + t;
      int nl = idx >> 3, kc = (idx & 7) * 8;
      bf16x8 o;
      #pragma unroll
      for (int ii = 0; ii < 8; ++ii) o[ii] = (bf16_t)tl[kc + ii][nl];
      *(bf16x8*)(wdst + (size_t)(n0 + nl) * 1024 + k0 + kc) = o;
    }
  }
}

// ---------------------------------------------------------------------------
// LN2 (fused split-K add, bf16 partials): z = z0 + z1 -> layernorm -> fp32
// ---------------------------------------------------------------------------
__global__ __launch_bounds__(256) void ln2_kernel(
    const bf16_t* __restrict__ z0, const bf16_t* __restrict__ z1,
    const float* __restrict__ g, const float* __restrict__ bta,
    float* __restrict__ out) {
  const int row = blockIdx.x;
  const int t = threadIdx.x, w = t >> 6, l = t & 63;
  bf16x4 a0 = *(const bf16x4*)(z0 + (size_t)row * 1024 + t * 4);
  bf16x4 a1 = *(const bf16x4*)(z1 + (size_t)row * 1024 + t * 4);
  float4 v;
  v.x = (float)a0[0] + (float)a1[0];
  v.y = (float)a0[1] + (float)a1[1];
  v.z = (float)a0[2] + (float)a1[2];
  v.w = (float)a0[3] + (float)a1[3];
  float s  = v.x + v.y + v.z + v.w;
  float s2 = v.x * v.x + v.y * v.y + v.z * v.z + v.w * v.w;
  #pragma unroll
  for (int off = 32; off >= 1; off >>= 1) {
    s  += __shfl_down(s, off);
    s2 += __shfl_down(s2, off);
  }
  __shared__ float red[8];
  if (l == 0) { red[w] = s; red[4 + w] = s2; }
  __syncthreads();
  s  = red[0] + red[1] + red[2] + red[3];
  s2 = red[4] + red[5] + red[6] + red[7];
  float mu  = s * (1.0f / 1024.0f);
  float var = s2 * (1.0f / 1024.0f) - mu * mu;
  float rs  = rsqrtf(var + 1e-5f);
  float4 gv = *(const float4*)(g + t * 4);
  float4 bv = *(const float4*)(bta + t * 4);
  float4 o;
  o.x = (v.x - mu) * rs * gv.x + bv.x;
  o.y = (v.y - mu) * rs * gv.y + bv.y;
  o.z = (v.z - mu) * rs * gv.z + bv.z;
  o.w = (v.w - mu) * rs * gv.w + bv.w;
  *(float4*)(out + (size_t)row * 1024 + t * 4) = o;
}

// ---------------------------------------------------------------------------
// V transpose: v bf16 [b,h,n,64] -> vT bf16 [b,h,64,n]   (n=2048)
// ---------------------------------------------------------------------------
__global__ __launch_bounds__(256) void vtrans_kernel(
    const bf16_t* __restrict__ v, bf16_t* __restrict__ vT) {
  __shared__ __align__(16) bf16_t tl[64][72];
  const int n0 = blockIdx.x * 64;
  const size_t bh = blockIdx.y;
  const int t = threadIdx.x;
  #pragma unroll
  for (int c = 0; c < 2; ++c) {
    int idx = c * 256 + t;
    int r = idx >> 3, c8 = (idx & 7) * 8;
    *(bf16x8*)&tl[r][c8] = *(const bf16x8*)(v + (bh * 2048 + n0 + r) * 64 + c8);
  }
  __syncthreads();
  #pragma unroll
  for (int c = 0; c < 2; ++c) {
    int idx = c * 256 + t;
    int d = idx >> 3, nc = (idx & 7) * 8;
    bf16x8 o;
    #pragma unroll
    for (int ii = 0; ii < 8; ++ii) o[ii] = tl[nc + ii][d];
    *(bf16x8*)(vT + (bh * 64 + d) * 2048 + n0 + nc) = o;
  }
}

// ---------------------------------------------------------------------------
// GEMM: C[M,N] = A[M,1024] @ Bt[N,1024]^T, bf16 in, fp32 acc.
// BK=64, XOR-swizzled staging. KSPLIT=2: kz=0 -> C0, kz=1 -> C1 (bf16
// partials). EPI=1: qkv split epilogue -> q(*0.125)/k/v bf16 [b,h,2048,64].
// ---------------------------------------------------------------------------
template <int EPI, int KSPLIT>
__global__ __launch_bounds__(256, 3) void gemm128_kernel(
    const bf16_t* __restrict__ A, const bf16_t* __restrict__ Bt,
    void* __restrict__ C0, void* __restrict__ C1, void* __restrict__ C2) {
  __shared__ __align__(16) bf16_t As[128 * 64];  // 16 KB
  __shared__ __align__(16) bf16_t Bs[128 * 64];  // 16 KB
  const int t = threadIdx.x;
  const int w = t >> 6, l = t & 63, l15 = l & 15, quad = l >> 4;
  const int wy = w >> 1, wx = w & 1;
  const int m0 = blockIdx.y * 128, n0 = blockIdx.x * 128;
  const int kz = (KSPLIT > 1) ? blockIdx.z : 0;
  const int kt0 = kz * (16 / KSPLIT), kt1 = kt0 + (16 / KSPLIT);

  const int r_l = l >> 3;              // row within 8-row chunk
  const int u_src = (l & 7) ^ r_l;     // swizzled source 8-elem unit
  const int rswz = l15 & 7;            // read-side swizzle key

  f32x4 acc[4][4];
  #pragma unroll
  for (int i = 0; i < 4; ++i)
    #pragma unroll
    for (int j = 0; j < 4; ++j) acc[i][j] = (f32x4)0.0f;

  for (int kt = kt0; kt < kt1; ++kt) {
    __syncthreads();
    #pragma unroll
    for (int c = 0; c < 4; ++c) {
      int idx = w * 4 + c;             // 16 chunks of 512 elems
      int row = idx * 8 + r_l;         // 0..127
      async_copy16(&As[idx * 512], A + (size_t)(m0 + row) * 1024 + kt * 64 + u_src * 8);
      async_copy16(&Bs[idx * 512], Bt + (size_t)(n0 + row) * 1024 + kt * 64 + u_src * 8);
    }
    __syncthreads();
    #pragma unroll
    for (int kk = 0; kk < 2; ++kk) {
      bf16x8 af[4], bfr[4];
      #pragma unroll
      for (int i = 0; i < 4; ++i)
        af[i] = *(const bf16x8*)&As[(wy * 64 + i * 16 + l15) * 64 + (((kk * 4 + quad) ^ rswz) * 8)];
      #pragma unroll
      for (int j = 0; j < 4; ++j)
        bfr[j] = *(const bf16x8*)&Bs[(wx * 64 + j * 16 + l15) * 64 + (((kk * 4 + quad) ^ rswz) * 8)];
      #pragma unroll
      for (int i = 0; i < 4; ++i)
        #pragma unroll
        for (int j = 0; j < 4; ++j)
          acc[i][j] = __builtin_amdgcn_mfma_f32_16x16x32_bf16(af[i], bfr[j], acc[i][j], 0, 0, 0);
    }
  }

  if (EPI == 0) {
    bf16_t* C = (bf16_t*)(kz == 0 ? C0 : C1);   // bf16 partial destinations
    #pragma unroll
    for (int i = 0; i < 4; ++i)
      #pragma unroll
      for (int j = 0; j < 4; ++j)
        #pragma unroll
        for (int r = 0; r < 4; ++r) {
          int m = m0 + wy * 64 + i * 16 + quad * 4 + r;
          int n = n0 + wx * 64 + j * 16 + l15;
          C[(size_t)m * 1024 + n] = (bf16_t)acc[i][j][r];
        }
  } else {
    int nb = n0 + wx * 64;
    int which = nb >> 10;
    int head = (nb & 1023) >> 6;
    bf16_t* dst = which == 0 ? (bf16_t*)C0 : which == 1 ? (bf16_t*)C1 : (bf16_t*)C2;
    float sc = which == 0 ? 0.125f : 1.0f;
    #pragma unroll
    for (int i = 0; i < 4; ++i)
      #pragma unroll
      for (int j = 0; j < 4; ++j)
        #pragma unroll
        for (int r = 0; r < 4; ++r) {
          int m = m0 + wy * 64 + i * 16 + quad * 4 + r;
          int bq = m >> 11, pos = m & 2047;
          int d = j * 16 + l15;
          dst[(((size_t)(bq * 16 + head)) * 2048 + pos) * 64 + d] =
              (bf16_t)(acc[i][j][r] * sc);
        }
  }
}

// ---------------------------------------------------------------------------
// Causal ReLU attention, R8: operand-swapped MFMA layouts.
// S-matmul: A=K, B=Q -> S^T in C-layout (lane col = query row i, reg rows =
// key j, 4 j-contiguous per lane) -> Ss[i][j] via 4 packed ds_write_b64/unit.
// PV: A=V^T, B=S(read as B-frag from Ss) -> O^T (lane col = i, regs = d),
// epilogue = 4 packed b64 stores per sub-tile.
// Block (h=bx, p=by, b=bz): sub-tiles tA=p, tB=31-p, uniform 17 iterations.
// K/V double-buffered two-tile staging via global_load_lds (swizzled).
// ---------------------------------------------------------------------------
__global__ __launch_bounds__(256, 2) void attn_kernel(
    const bf16_t* __restrict__ q, const bf16_t* __restrict__ k,
    const bf16_t* __restrict__ vT, bf16_t* __restrict__ out) {
  __shared__ __align__(16) bf16_t Ks[2][128 * 64];   // 2 x 16 KB (two 64-key halves)
  __shared__ __align__(16) bf16_t Vts[2][128 * 64];  // 2 x 16 KB
  __shared__ __align__(16) bf16_t Ss[64 * 72];       // 9 KB, wave-private rows

  const int h = blockIdx.x, p = blockIdx.y, b = blockIdx.z;
  const int t = threadIdx.x;
  const int w = t >> 6, l = t & 63, l15 = l & 15, quad = l >> 4;
  const size_t bh = (size_t)(b * 16 + h);
  const int tB = 31 - p;

  const int r_l = l >> 3;            // row within 8-row chunk
  const int u_g = (l & 7) ^ r_l;     // swizzled source 8-elem unit
  const int rswz = l15 & 7;          // read-side swizzle key

  auto stage_tile = [&](int buf, int half, int kt2) {
    #pragma unroll
    for (int c = 0; c < 2; ++c) {
      int idx = w * 2 + c;                    // 0..7
      int row = idx * 8 + r_l;                // 0..63
      async_copy16(&Ks[buf][half * 4096 + idx * 512],
                   k + (bh * 2048 + kt2 * 64 + row) * 64 + u_g * 8);
      async_copy16(&Vts[buf][half * 4096 + idx * 512],
                   vT + (bh * 64 + row) * 2048 + kt2 * 64 + u_g * 8);
    }
  };
  auto stage_it = [&](int it, int buf) {
    if (it <= p) {
      stage_tile(buf, 0, it);
    } else {
      int base = p + 1 + 2 * (it - p - 1);
      stage_tile(buf, 0, base);
      int k2 = base + 1; if (k2 > 31) k2 = 31;  // clamp (compute skips > tB)
      stage_tile(buf, 1, k2);
    }
  };

  // read a staged tile's K/V fragments from LDS (once per tile)
  auto load_lds = [&](const bf16_t* Kb, const bf16_t* Vb,
                      bf16x8 (&bk)[2][4], bf16x8 (&bv)[2][4]) {
    #pragma unroll
    for (int kk = 0; kk < 2; ++kk)
      #pragma unroll
      for (int tj = 0; tj < 4; ++tj) {
        int u = ((kk * 4 + quad) ^ rswz) * 8;
        bk[kk][tj] = *(const bf16x8*)&Kb[(tj * 16 + l15) * 64 + u];
        bv[kk][tj] = *(const bf16x8*)&Vb[(tj * 16 + l15) * 64 + u];
      }
  };

  bf16x8 qa[2][2];   // B-operand fragments: lane l15 = query row, k = d
  {
    int rA = p * 64 + w * 16, rB = tB * 64 + w * 16;
    #pragma unroll
    for (int kk = 0; kk < 2; ++kk) {
      qa[0][kk] = *(const bf16x8*)(q + (bh * 2048 + rA + l15) * 64 + kk * 32 + quad * 8);
      qa[1][kk] = *(const bf16x8*)(q + (bh * 2048 + rB + l15) * 64 + kk * 32 + quad * 8);
    }
  }

  // acc[tj] = O^T block: lane col = i (l15), regs = d = tj*16 + quad*4 + r
  f32x4 acc0[4], acc1[4];
  #pragma unroll
  for (int tj = 0; tj < 4; ++tj) { acc0[tj] = (f32x4)0.0f; acc1[tj] = (f32x4)0.0f; }

  // one 64-key unit: S^T = K.Q^T (relu+mask, packed write), O^T += V^T.S
  auto unit = [&](f32x4 (&accr)[4], bf16x8 (&qf)[2],
                  bf16x8 (&bk)[2][4], bf16x8 (&bv)[2][4], bool dg) {
    f32x4 sacc[4];  // sacc[tj]: lane col = i (l15), regs = j = tj*16+quad*4+r
    #pragma unroll
    for (int tj = 0; tj < 4; ++tj) sacc[tj] = (f32x4)0.0f;
    #pragma unroll
    for (int kk = 0; kk < 2; ++kk)
      #pragma unroll
      for (int tj = 0; tj < 4; ++tj)
        sacc[tj] = __builtin_amdgcn_mfma_f32_16x16x32_bf16(bk[kk][tj], qf[kk], sacc[tj], 0, 0, 0);
    // relu + causal mask; 4 j-contiguous values -> one b64 store per tj
    #pragma unroll
    for (int tj = 0; tj < 4; ++tj) {
      bf16x4 pk;
      #pragma unroll
      for (int r = 0; r < 4; ++r) {
        float v = fmaxf(sacc[tj][r], 0.0f);
        if (dg && (tj * 16 + quad * 4 + r > w * 16 + l15)) v = 0.0f;
        pk[r] = (bf16_t)v;
      }
      *(bf16x4*)&Ss[(w * 16 + l15) * 72 + tj * 16 + quad * 4] = pk;
    }
    // O^T += V^T . S  (S read as B-fragment: lane l15 = i, k = j contiguous)
    #pragma unroll
    for (int kk = 0; kk < 2; ++kk) {
      bf16x8 as_ = *(const bf16x8*)&Ss[(w * 16 + l15) * 72 + kk * 32 + quad * 8];
      #pragma unroll
      for (int tj = 0; tj < 4; ++tj)
        accr[tj] = __builtin_amdgcn_mfma_f32_16x16x32_bf16(bv[kk][tj], as_, accr[tj], 0, 0, 0);
    }
  };

  stage_it(0, 0);
  for (int it = 0; it < 17; ++it) {
    __syncthreads();  // drains this buffer's async loads; fences reuse
    if (it + 1 < 17) stage_it(it + 1, (it + 1) & 1);
    const int buf = it & 1;
    bf16x8 bk[2][4], bv[2][4];
    load_lds(&Ks[buf][0], &Vts[buf][0], bk, bv);
    if (it <= p) {
      unit(acc0, qa[0], bk, bv, it == p);      // fragments shared by both units
      unit(acc1, qa[1], bk, bv, false);
    } else {
      int base = p + 1 + 2 * (it - p - 1);
      unit(acc1, qa[1], bk, bv, base == tB);
      if (base + 1 <= tB) {                    // reuse the same array: one set live
        load_lds(&Ks[buf][4096], &Vts[buf][4096], bk, bv);
        unit(acc1, qa[1], bk, bv, base + 1 == tB);
      }
    }
  }

  // epilogue: O^T regs -> out[b][pos=i][h*64+d], 4 d-contiguous per store
  #pragma unroll
  for (int tj = 0; tj < 4; ++tj) {
    bf16x4 p0, p1;
    #pragma unroll
    for (int r = 0; r < 4; ++r) { p0[r] = (bf16_t)acc0[tj][r]; p1[r] = (bf16_t)acc1[tj][r]; }
    int posA = p * 64 + w * 16 + l15;
    int posB = tB * 64 + w * 16 + l15;
    int col = h * 64 + tj * 16 + quad * 4;
    *(bf16x4*)(out + ((size_t)b * 2048 + posA) * 1024 + col) = p0;
    *(bf16x4*)(out + ((size_t)b * 2048 + posB) * 1024 + col) = p1;
  }
}

// ---------------------------------------------------------------------------
// launch
// ---------------------------------------------------------------------------
extern "C" void kernel_launch(void* const* d_in, const int* in_sizes, int n_in,
                              void* d_out, int out_size, void* d_ws, size_t ws_size,
                              hipStream_t stream) {
  (void)in_sizes; (void)n_in; (void)out_size; (void)ws_size;
  const float* x     = (const float*)d_in[0];
  const float* ln1_g = (const float*)d_in[1];
  const float* ln1_b = (const float*)d_in[2];
  const float* w_qkv = (const float*)d_in[3];
  const float* w_out = (const float*)d_in[4];
  const float* ln2_g = (const float*)d_in[5];
  const float* ln2_b = (const float*)d_in[6];
  float* out = (float*)d_out;

  char* ws = (char*)d_ws;
  bf16_t* xn     = (bf16_t*)(ws + 0);          //  8,388,608  [4096,1024]
  bf16_t* wqkvT  = (bf16_t*)(ws + 8388608);    //  6,291,456  [3072,1024]
  bf16_t* woutT  = (bf16_t*)(ws + 14680064);   //  2,097,152  [1024,1024]
  bf16_t* qb     = (bf16_t*)(ws + 16777216);   //  8,388,608  [2,16,2048,64]
  bf16_t* kb     = (bf16_t*)(ws + 25165824);   //  8,388,608
  bf16_t* vb     = (bf16_t*)(ws + 33554432);   //  8,388,608
  bf16_t* vTb    = (bf16_t*)(ws + 41943040);   //  8,388,608  [2,16,64,2048]
  bf16_t* ao     = (bf16_t*)(ws + 50331648);   //  8,388,608  [4096,1024]
  bf16_t* zb0    = (bf16_t*)(ws + 58720256);   //  8,388,608  [4096,1024] bf16 partial
  bf16_t* zb1    = (bf16_t*)(ws + 67108864);   //  8,388,608  bf16 partial

  prep_kernel<<<5120, 256, 0, stream>>>(x, ln1_g, ln1_b, xn, w_qkv, wqkvT, w_out, woutT);
  gemm128_kernel<1, 1><<<dim3(24, 32), 256, 0, stream>>>(xn, wqkvT, qb, kb, vb);
  vtrans_kernel<<<dim3(32, 32), 256, 0, stream>>>(vb, vTb);
  attn_kernel<<<dim3(16, 16, 2), 256, 0, stream>>>(qb, kb, vTb, ao);
  gemm128_kernel<0, 2><<<dim3(8, 32, 2), 256, 0, stream>>>(ao, woutT, zb0, zb1, nullptr);
  ln2_kernel<<<4096, 256, 0, stream>>>(zb0, zb1, ln2_g, ln2_b, out);
}

// Round 10
// 176.026 us; speedup vs baseline: 1.7688x; 1.0144x over previous
//
#include <hip/hip_runtime.h>
#include <cstdint>
#include <cstddef>

// ---------------------------------------------------------------------------
// ReLA block: y = LN2( (causal_relu( (LN1(x)Wq*s) (LN1(x)Wk)^T ) (LN1(x)Wv)) Wout )
// x: [2,2048,1024] fp32. HEADS=16, DIM_HEAD=64, DIM=1024. Output fp32.
// bf16 MFMA (16x16x32) everywhere, fp32 accumulate.
// R9: attn iteration interleaved — S-matmuls of both units issued before the
//     Ss round-trips / PV matmuls (independent MFMA streams hide the LDS
//     write->read latency and MFMA dep-chains). Phase-2 fragment loads for
//     both staged tiles hoisted. Single Ss buffer (same-wave LDS ordering).
// ---------------------------------------------------------------------------

typedef __bf16 bf16_t;
typedef __bf16 bf16x8 __attribute__((ext_vector_type(8)));
typedef __bf16 bf16x4 __attribute__((ext_vector_type(4)));
typedef float  f32x4  __attribute__((ext_vector_type(4)));

#define DEV_INLINE __device__ __forceinline__

// async global->LDS, 16B per lane. LDS dest is wave-uniform base + lane*16.
DEV_INLINE void async_copy16(void* lds, const void* g) {
  __builtin_amdgcn_global_load_lds(
      (__attribute__((address_space(1))) void*)(g),
      (__attribute__((address_space(3))) void*)(lds), 16, 0, 0);
}

// ---------------------------------------------------------------------------
// prep: fused LN1 (blocks 0..4095) + wtrans(w_qkv) (4096..4863) +
//       wtrans(w_out) (4864..5119)
// ---------------------------------------------------------------------------
__global__ __launch_bounds__(256) void prep_kernel(
    const float* __restrict__ x, const float* __restrict__ g1,
    const float* __restrict__ b1, bf16_t* __restrict__ xn,
    const float* __restrict__ w_qkv, bf16_t* __restrict__ wqkvT,
    const float* __restrict__ w_out, bf16_t* __restrict__ woutT) {
  const int bid = blockIdx.x;
  const int t = threadIdx.x;
  if (bid < 4096) {
    // ---- LN1 row ----
    const int w = t >> 6, l = t & 63;
    const float* xr = x + (size_t)bid * 1024;
    float4 v = *(const float4*)(xr + t * 4);
    float s  = v.x + v.y + v.z + v.w;
    float s2 = v.x * v.x + v.y * v.y + v.z * v.z + v.w * v.w;
    #pragma unroll
    for (int off = 32; off >= 1; off >>= 1) {
      s  += __shfl_down(s, off);
      s2 += __shfl_down(s2, off);
    }
    __shared__ float red[8];
    if (l == 0) { red[w] = s; red[4 + w] = s2; }
    __syncthreads();
    s  = red[0] + red[1] + red[2] + red[3];
    s2 = red[4] + red[5] + red[6] + red[7];
    float mu  = s * (1.0f / 1024.0f);
    float var = s2 * (1.0f / 1024.0f) - mu * mu;
    float rs  = rsqrtf(var + 1e-5f);
    float4 gv = *(const float4*)(g1 + t * 4);
    float4 bv = *(const float4*)(b1 + t * 4);
    bf16x4 o;
    o[0] = (bf16_t)((v.x - mu) * rs * gv.x + bv.x);
    o[1] = (bf16_t)((v.y - mu) * rs * gv.y + bv.y);
    o[2] = (bf16_t)((v.z - mu) * rs * gv.z + bv.z);
    o[3] = (bf16_t)((v.w - mu) * rs * gv.w + bv.w);
    *(bf16x4*)(xn + (size_t)bid * 1024 + t * 4) = o;
  } else {
    // ---- weight transpose+convert: 64x64 tile ----
    const float* wsrc; bf16_t* wdst; int N, tile;
    if (bid < 4864) { wsrc = w_qkv; wdst = wqkvT; N = 3072; tile = bid - 4096; }
    else            { wsrc = w_out; wdst = woutT; N = 1024; tile = bid - 4864; }
    const int ntiles = N >> 6;
    const int n0 = (tile % ntiles) * 64, k0 = (tile / ntiles) * 64;
    __shared__ __align__(16) float tl[64][68];
    #pragma unroll
    for (int c = 0; c < 4; ++c) {
      int idx = c * 256 + t;
      int r = idx >> 4, c4 = (idx & 15) * 4;
      *(float4*)&tl[r][c4] = *(const float4*)(wsrc + (size_t)(k0 + r) * N + n0 + c4);
    }
    __syncthreads();
    #pragma unroll
    for (int c = 0; c < 2; ++c) {
      int idx = c * 256 + t;
      int nl = idx >> 3, kc = (idx & 7) * 8;
      bf16x8 o;
      #pragma unroll
      for (int ii = 0; ii < 8; ++ii) o[ii] = (bf16_t)tl[kc + ii][nl];
      *(bf16x8*)(wdst + (size_t)(n0 + nl) * 1024 + k0 + kc) = o;
    }
  }
}

// ---------------------------------------------------------------------------
// LN2 (fused split-K add, bf16 partials): z = z0 + z1 -> layernorm -> fp32
// ---------------------------------------------------------------------------
__global__ __launch_bounds__(256) void ln2_kernel(
    const bf16_t* __restrict__ z0, const bf16_t* __restrict__ z1,
    const float* __restrict__ g, const float* __restrict__ bta,
    float* __restrict__ out) {
  const int row = blockIdx.x;
  const int t = threadIdx.x, w = t >> 6, l = t & 63;
  bf16x4 a0 = *(const bf16x4*)(z0 + (size_t)row * 1024 + t * 4);
  bf16x4 a1 = *(const bf16x4*)(z1 + (size_t)row * 1024 + t * 4);
  float4 v;
  v.x = (float)a0[0] + (float)a1[0];
  v.y = (float)a0[1] + (float)a1[1];
  v.z = (float)a0[2] + (float)a1[2];
  v.w = (float)a0[3] + (float)a1[3];
  float s  = v.x + v.y + v.z + v.w;
  float s2 = v.x * v.x + v.y * v.y + v.z * v.z + v.w * v.w;
  #pragma unroll
  for (int off = 32; off >= 1; off >>= 1) {
    s  += __shfl_down(s, off);
    s2 += __shfl_down(s2, off);
  }
  __shared__ float red[8];
  if (l == 0) { red[w] = s; red[4 + w] = s2; }
  __syncthreads();
  s  = red[0] + red[1] + red[2] + red[3];
  s2 = red[4] + red[5] + red[6] + red[7];
  float mu  = s * (1.0f / 1024.0f);
  float var = s2 * (1.0f / 1024.0f) - mu * mu;
  float rs  = rsqrtf(var + 1e-5f);
  float4 gv = *(const float4*)(g + t * 4);
  float4 bv = *(const float4*)(bta + t * 4);
  float4 o;
  o.x = (v.x - mu) * rs * gv.x + bv.x;
  o.y = (v.y - mu) * rs * gv.y + bv.y;
  o.z = (v.z - mu) * rs * gv.z + bv.z;
  o.w = (v.w - mu) * rs * gv.w + bv.w;
  *(float4*)(out + (size_t)row * 1024 + t * 4) = o;
}

// ---------------------------------------------------------------------------
// V transpose: v bf16 [b,h,n,64] -> vT bf16 [b,h,64,n]   (n=2048)
// ---------------------------------------------------------------------------
__global__ __launch_bounds__(256) void vtrans_kernel(
    const bf16_t* __restrict__ v, bf16_t* __restrict__ vT) {
  __shared__ __align__(16) bf16_t tl[64][72];
  const int n0 = blockIdx.x * 64;
  const size_t bh = blockIdx.y;
  const int t = threadIdx.x;
  #pragma unroll
  for (int c = 0; c < 2; ++c) {
    int idx = c * 256 + t;
    int r = idx >> 3, c8 = (idx & 7) * 8;
    *(bf16x8*)&tl[r][c8] = *(const bf16x8*)(v + (bh * 2048 + n0 + r) * 64 + c8);
  }
  __syncthreads();
  #pragma unroll
  for (int c = 0; c < 2; ++c) {
    int idx = c * 256 + t;
    int d = idx >> 3, nc = (idx & 7) * 8;
    bf16x8 o;
    #pragma unroll
    for (int ii = 0; ii < 8; ++ii) o[ii] = tl[nc + ii][d];
    *(bf16x8*)(vT + (bh * 64 + d) * 2048 + n0 + nc) = o;
  }
}

// ---------------------------------------------------------------------------
// GEMM: C[M,N] = A[M,1024] @ Bt[N,1024]^T, bf16 in, fp32 acc.
// BK=64, XOR-swizzled staging. KSPLIT=2: kz=0 -> C0, kz=1 -> C1 (bf16
// partials). EPI=1: qkv split epilogue -> q(*0.125)/k/v bf16 [b,h,2048,64].
// ---------------------------------------------------------------------------
template <int EPI, int KSPLIT>
__global__ __launch_bounds__(256, 3) void gemm128_kernel(
    const bf16_t* __restrict__ A, const bf16_t* __restrict__ Bt,
    void* __restrict__ C0, void* __restrict__ C1, void* __restrict__ C2) {
  __shared__ __align__(16) bf16_t As[128 * 64];  // 16 KB
  __shared__ __align__(16) bf16_t Bs[128 * 64];  // 16 KB
  const int t = threadIdx.x;
  const int w = t >> 6, l = t & 63, l15 = l & 15, quad = l >> 4;
  const int wy = w >> 1, wx = w & 1;
  const int m0 = blockIdx.y * 128, n0 = blockIdx.x * 128;
  const int kz = (KSPLIT > 1) ? blockIdx.z : 0;
  const int kt0 = kz * (16 / KSPLIT), kt1 = kt0 + (16 / KSPLIT);

  const int r_l = l >> 3;              // row within 8-row chunk
  const int u_src = (l & 7) ^ r_l;     // swizzled source 8-elem unit
  const int rswz = l15 & 7;            // read-side swizzle key

  f32x4 acc[4][4];
  #pragma unroll
  for (int i = 0; i < 4; ++i)
    #pragma unroll
    for (int j = 0; j < 4; ++j) acc[i][j] = (f32x4)0.0f;

  for (int kt = kt0; kt < kt1; ++kt) {
    __syncthreads();
    #pragma unroll
    for (int c = 0; c < 4; ++c) {
      int idx = w * 4 + c;             // 16 chunks of 512 elems
      int row = idx * 8 + r_l;         // 0..127
      async_copy16(&As[idx * 512], A + (size_t)(m0 + row) * 1024 + kt * 64 + u_src * 8);
      async_copy16(&Bs[idx * 512], Bt + (size_t)(n0 + row) * 1024 + kt * 64 + u_src * 8);
    }
    __syncthreads();
    #pragma unroll
    for (int kk = 0; kk < 2; ++kk) {
      bf16x8 af[4], bfr[4];
      #pragma unroll
      for (int i = 0; i < 4; ++i)
        af[i] = *(const bf16x8*)&As[(wy * 64 + i * 16 + l15) * 64 + (((kk * 4 + quad) ^ rswz) * 8)];
      #pragma unroll
      for (int j = 0; j < 4; ++j)
        bfr[j] = *(const bf16x8*)&Bs[(wx * 64 + j * 16 + l15) * 64 + (((kk * 4 + quad) ^ rswz) * 8)];
      #pragma unroll
      for (int i = 0; i < 4; ++i)
        #pragma unroll
        for (int j = 0; j < 4; ++j)
          acc[i][j] = __builtin_amdgcn_mfma_f32_16x16x32_bf16(af[i], bfr[j], acc[i][j], 0, 0, 0);
    }
  }

  if (EPI == 0) {
    bf16_t* C = (bf16_t*)(kz == 0 ? C0 : C1);   // bf16 partial destinations
    #pragma unroll
    for (int i = 0; i < 4; ++i)
      #pragma unroll
      for (int j = 0; j < 4; ++j)
        #pragma unroll
        for (int r = 0; r < 4; ++r) {
          int m = m0 + wy * 64 + i * 16 + quad * 4 + r;
          int n = n0 + wx * 64 + j * 16 + l15;
          C[(size_t)m * 1024 + n] = (bf16_t)acc[i][j][r];
        }
  } else {
    int nb = n0 + wx * 64;
    int which = nb >> 10;
    int head = (nb & 1023) >> 6;
    bf16_t* dst = which == 0 ? (bf16_t*)C0 : which == 1 ? (bf16_t*)C1 : (bf16_t*)C2;
    float sc = which == 0 ? 0.125f : 1.0f;
    #pragma unroll
    for (int i = 0; i < 4; ++i)
      #pragma unroll
      for (int j = 0; j < 4; ++j)
        #pragma unroll
        for (int r = 0; r < 4; ++r) {
          int m = m0 + wy * 64 + i * 16 + quad * 4 + r;
          int bq = m >> 11, pos = m & 2047;
          int d = j * 16 + l15;
          dst[(((size_t)(bq * 16 + head)) * 2048 + pos) * 64 + d] =
              (bf16_t)(acc[i][j][r] * sc);
        }
  }
}

// ---------------------------------------------------------------------------
// Causal ReLU attention, R9: interleaved S/PV pipeline.
// Operand-swapped layouts (R8): S^T = K.Q^T (4 packed b64 Ss writes/unit),
// O^T += V^T.S (packed b64 epilogue). Per iteration, BOTH units' S-matmuls
// issue before any Ss round-trip -> independent MFMA work hides the LDS
// write->read latency. Same-wave LDS ordering makes the shared Ss safe.
// Block (h=bx, p=by, b=bz): sub-tiles tA=p, tB=31-p, uniform 17 iterations.
// K/V double-buffered two-tile staging via global_load_lds (swizzled).
// ---------------------------------------------------------------------------
__global__ __launch_bounds__(256, 2) void attn_kernel(
    const bf16_t* __restrict__ q, const bf16_t* __restrict__ k,
    const bf16_t* __restrict__ vT, bf16_t* __restrict__ out) {
  __shared__ __align__(16) bf16_t Ks[2][128 * 64];   // 2 x 16 KB (two 64-key halves)
  __shared__ __align__(16) bf16_t Vts[2][128 * 64];  // 2 x 16 KB
  __shared__ __align__(16) bf16_t Ss[64 * 72];       // 9 KB, wave-private rows

  const int h = blockIdx.x, p = blockIdx.y, b = blockIdx.z;
  const int t = threadIdx.x;
  const int w = t >> 6, l = t & 63, l15 = l & 15, quad = l >> 4;
  const size_t bh = (size_t)(b * 16 + h);
  const int tB = 31 - p;

  const int r_l = l >> 3;            // row within 8-row chunk
  const int u_g = (l & 7) ^ r_l;     // swizzled source 8-elem unit
  const int rswz = l15 & 7;          // read-side swizzle key

  auto stage_tile = [&](int buf, int half, int kt2) {
    #pragma unroll
    for (int c = 0; c < 2; ++c) {
      int idx = w * 2 + c;                    // 0..7
      int row = idx * 8 + r_l;                // 0..63
      async_copy16(&Ks[buf][half * 4096 + idx * 512],
                   k + (bh * 2048 + kt2 * 64 + row) * 64 + u_g * 8);
      async_copy16(&Vts[buf][half * 4096 + idx * 512],
                   vT + (bh * 64 + row) * 2048 + kt2 * 64 + u_g * 8);
    }
  };
  auto stage_it = [&](int it, int buf) {
    if (it <= p) {
      stage_tile(buf, 0, it);
    } else {
      int base = p + 1 + 2 * (it - p - 1);
      stage_tile(buf, 0, base);
      int k2 = base + 1; if (k2 > 31) k2 = 31;  // clamp (compute skips > tB)
      stage_tile(buf, 1, k2);
    }
  };

  // read a staged tile's K/V fragments from LDS (once per tile)
  auto load_lds = [&](const bf16_t* Kb, const bf16_t* Vb,
                      bf16x8 (&bk)[2][4], bf16x8 (&bv)[2][4]) {
    #pragma unroll
    for (int kk = 0; kk < 2; ++kk)
      #pragma unroll
      for (int tj = 0; tj < 4; ++tj) {
        int u = ((kk * 4 + quad) ^ rswz) * 8;
        bk[kk][tj] = *(const bf16x8*)&Kb[(tj * 16 + l15) * 64 + u];
        bv[kk][tj] = *(const bf16x8*)&Vb[(tj * 16 + l15) * 64 + u];
      }
  };

  bf16x8 qa[2][2];   // B-operand fragments: lane l15 = query row, k = d
  {
    int rA = p * 64 + w * 16, rB = tB * 64 + w * 16;
    #pragma unroll
    for (int kk = 0; kk < 2; ++kk) {
      qa[0][kk] = *(const bf16x8*)(q + (bh * 2048 + rA + l15) * 64 + kk * 32 + quad * 8);
      qa[1][kk] = *(const bf16x8*)(q + (bh * 2048 + rB + l15) * 64 + kk * 32 + quad * 8);
    }
  }

  // acc[tj] = O^T block: lane col = i (l15), regs = d = tj*16 + quad*4 + r
  f32x4 acc0[4], acc1[4];
  #pragma unroll
  for (int tj = 0; tj < 4; ++tj) { acc0[tj] = (f32x4)0.0f; acc1[tj] = (f32x4)0.0f; }

  // S^T matmul into registers (no LDS)
  auto sU = [&](f32x4 (&sacc)[4], bf16x8 (&qf)[2], bf16x8 (&bk)[2][4]) {
    #pragma unroll
    for (int tj = 0; tj < 4; ++tj) sacc[tj] = (f32x4)0.0f;
    #pragma unroll
    for (int kk = 0; kk < 2; ++kk)
      #pragma unroll
      for (int tj = 0; tj < 4; ++tj)
        sacc[tj] = __builtin_amdgcn_mfma_f32_16x16x32_bf16(bk[kk][tj], qf[kk], sacc[tj], 0, 0, 0);
  };
  // relu + mask + packed Ss write
  auto wU = [&](f32x4 (&sacc)[4], bool dg) {
    #pragma unroll
    for (int tj = 0; tj < 4; ++tj) {
      bf16x4 pk;
      #pragma unroll
      for (int r = 0; r < 4; ++r) {
        float v = fmaxf(sacc[tj][r], 0.0f);
        if (dg && (tj * 16 + quad * 4 + r > w * 16 + l15)) v = 0.0f;
        pk[r] = (bf16_t)v;
      }
      *(bf16x4*)&Ss[(w * 16 + l15) * 72 + tj * 16 + quad * 4] = pk;
    }
  };
  // PV: read Ss as B-fragment, O^T += V^T.S
  auto pU = [&](f32x4 (&accr)[4], bf16x8 (&bv)[2][4]) {
    #pragma unroll
    for (int kk = 0; kk < 2; ++kk) {
      bf16x8 as_ = *(const bf16x8*)&Ss[(w * 16 + l15) * 72 + kk * 32 + quad * 8];
      #pragma unroll
      for (int tj = 0; tj < 4; ++tj)
        accr[tj] = __builtin_amdgcn_mfma_f32_16x16x32_bf16(bv[kk][tj], as_, accr[tj], 0, 0, 0);
    }
  };

  stage_it(0, 0);
  for (int it = 0; it < 17; ++it) {
    __syncthreads();  // drains this buffer's async loads; fences reuse
    if (it + 1 < 17) stage_it(it + 1, (it + 1) & 1);
    const int buf = it & 1;
    if (it <= p) {
      bf16x8 bk[2][4], bv[2][4];
      load_lds(&Ks[buf][0], &Vts[buf][0], bk, bv);
      f32x4 s0[4], s1[4];
      sU(s0, qa[0], bk);          // independent MFMA streams back-to-back
      sU(s1, qa[1], bk);
      wU(s0, it == p); pU(acc0, bv);
      wU(s1, false);   pU(acc1, bv);
    } else {
      int base = p + 1 + 2 * (it - p - 1);
      bool second = (base + 1 <= tB);           // block-uniform
      bf16x8 bk1[2][4], bv1[2][4], bk2[2][4], bv2[2][4];
      load_lds(&Ks[buf][0], &Vts[buf][0], bk1, bv1);
      if (second) load_lds(&Ks[buf][4096], &Vts[buf][4096], bk2, bv2);
      f32x4 s0[4], s1[4];
      sU(s0, qa[1], bk1);
      if (second) sU(s1, qa[1], bk2);
      wU(s0, base == tB); pU(acc1, bv1);
      if (second) { wU(s1, base + 1 == tB); pU(acc1, bv2); }
    }
  }

  // epilogue: O^T regs -> out[b][pos=i][h*64+d], 4 d-contiguous per store
  #pragma unroll
  for (int tj = 0; tj < 4; ++tj) {
    bf16x4 p0, p1;
    #pragma unroll
    for (int r = 0; r < 4; ++r) { p0[r] = (bf16_t)acc0[tj][r]; p1[r] = (bf16_t)acc1[tj][r]; }
    int posA = p * 64 + w * 16 + l15;
    int posB = tB * 64 + w * 16 + l15;
    int col = h * 64 + tj * 16 + quad * 4;
    *(bf16x4*)(out + ((size_t)b * 2048 + posA) * 1024 + col) = p0;
    *(bf16x4*)(out + ((size_t)b * 2048 + posB) * 1024 + col) = p1;
  }
}

// ---------------------------------------------------------------------------
// launch
// ---------------------------------------------------------------------------
extern "C" void kernel_launch(void* const* d_in, const int* in_sizes, int n_in,
                              void* d_out, int out_size, void* d_ws, size_t ws_size,
                              hipStream_t stream) {
  (void)in_sizes; (void)n_in; (void)out_size; (void)ws_size;
  const float* x     = (const float*)d_in[0];
  const float* ln1_g = (const float*)d_in[1];
  const float* ln1_b = (const float*)d_in[2];
  const float* w_qkv = (const float*)d_in[3];
  const float* w_out = (const float*)d_in[4];
  const float* ln2_g = (const float*)d_in[5];
  const float* ln2_b = (const float*)d_in[6];
  float* out = (float*)d_out;

  char* ws = (char*)d_ws;
  bf16_t* xn     = (bf16_t*)(ws + 0);          //  8,388,608  [4096,1024]
  bf16_t* wqkvT  = (bf16_t*)(ws + 8388608);    //  6,291,456  [3072,1024]
  bf16_t* woutT  = (bf16_t*)(ws + 14680064);   //  2,097,152  [1024,1024]
  bf16_t* qb     = (bf16_t*)(ws + 16777216);   //  8,388,608  [2,16,2048,64]
  bf16_t* kb     = (bf16_t*)(ws + 25165824);   //  8,388,608
  bf16_t* vb     = (bf16_t*)(ws + 33554432);   //  8,388,608
  bf16_t* vTb    = (bf16_t*)(ws + 41943040);   //  8,388,608  [2,16,64,2048]
  bf16_t* ao     = (bf16_t*)(ws + 50331648);   //  8,388,608  [4096,1024]
  bf16_t* zb0    = (bf16_t*)(ws + 58720256);   //  8,388,608  [4096,1024] bf16 partial
  bf16_t* zb1    = (bf16_t*)(ws + 67108864);   //  8,388,608  bf16 partial

  prep_kernel<<<5120, 256, 0, stream>>>(x, ln1_g, ln1_b, xn, w_qkv, wqkvT, w_out, woutT);
  gemm128_kernel<1, 1><<<dim3(24, 32), 256, 0, stream>>>(xn, wqkvT, qb, kb, vb);
  vtrans_kernel<<<dim3(32, 32), 256, 0, stream>>>(vb, vTb);
  attn_kernel<<<dim3(16, 16, 2), 256, 0, stream>>>(qb, kb, vTb, ao);
  gemm128_kernel<0, 2><<<dim3(8, 32, 2), 256, 0, stream>>>(ao, woutT, zb0, zb1, nullptr);
  ln2_kernel<<<4096, 256, 0, stream>>>(zb0, zb1, ln2_g, ln2_b, out);
}